// Round 17
// baseline (153.548 us; speedup 1.0000x reference)
//
#include <hip/hip_runtime.h>
#include <hip/hip_bf16.h>

#define BB 32
#define SS 1600
#define DD 128
#define DFFN 2048
#define S2N 3200
#define RS 136  // LDS row stride in bf16 elems (128 + 8 pad)

typedef __attribute__((ext_vector_type(8))) short short8;
typedef __attribute__((ext_vector_type(4))) float floatx4;
typedef unsigned int u32;
typedef unsigned short u16;

__device__ __forceinline__ u32 encf(float f) {
  u32 u = __float_as_uint(f);
  return (u & 0x80000000u) ? ~u : (u | 0x80000000u);
}
__device__ __forceinline__ float decf(u32 e) {
  u32 u = (e & 0x80000000u) ? (e & 0x7fffffffu) : ~e;
  return __uint_as_float(u);
}
// fast RNE fp32->bf16 (finite data; matches library rounding)
__device__ __forceinline__ u16 f2b(float x) {
  u32 u = __float_as_uint(x);
  return (u16)((u + 0x7FFFu + ((u >> 16) & 1u)) >> 16);
}
__device__ __forceinline__ u32 packb2(float lo, float hi) {
  return (u32)f2b(lo) | ((u32)f2b(hi) << 16);
}
__device__ __forceinline__ float sigm(float x) { return 1.f / (1.f + __expf(-x)); }

// ---------------- K1: fused prep, GRID-STRIDED (512 blocks x ~3 units) ----------------
// units [0,800): 128-row q/k projection tile + l2norm (r13 body verbatim)
// units [800,1476): gate tiles (paired fragment layout) + m1u/m2u init
// 512 blocks = exactly the 2-blocks/CU LDS residency cap, so resident parallelism is
// unchanged while block-issue count drops 1476 -> 512.
__global__ __launch_bounds__(256) void k_prep(const float* __restrict__ tgt,
                                              const float* __restrict__ memin,
                                              const float* __restrict__ w1,
                                              const float* __restrict__ b1,
                                              const float* __restrict__ se,
                                              u16* __restrict__ qb, u16* __restrict__ kb,
                                              u16* __restrict__ gT2,
                                              u32* __restrict__ m1u, u32* __restrict__ m2u) {
  __shared__ u16 sA[128 * RS];
  __shared__ u16 sB[128 * RS];
  __shared__ float sq[128];
  int tid = threadIdx.x;
  int lane = tid & 63, wv = tid >> 6;
  int wr = wv >> 1, wc = wv & 1;
  int l15 = lane & 15, lg = lane >> 4;

  for (int unit = blockIdx.x; unit < 1476; unit += 512) {
    __syncthreads();  // fence LDS reuse across loop iterations (uniform)

    if (unit >= 800) {  // ---- gate-tile build + max-array init (no LDS) ----
      int bid = unit - 800;  // 0..675
      int ii = bid * 256 + tid;
      if (ii < BB * SS) {  // 0 encodes "below every finite float"
        m1u[ii] = 0u;
        m2u[ii] = 0u;
      }
      int r2 = bid >> 2, mi = bid & 3;  // quarter-tile per block
      int sy = r2 / 13, tx = r2 - sy * 13;
      int s0 = min(sy * 128, SS - 128);
      int t0 = min(tx * 128, SS - 128);
      int srow = s0 + wr * 64 + mi * 16 + lg * 4;
      u16* tb = gT2 + (size_t)r2 * 16384 + wv * 4096 + lane * 8;
      for (int ni = 0; ni < 4; ++ni) {
        int tcol = t0 + wc * 64 + ni * 16 + l15;
        const float* sp = se + (size_t)srow * SS + tcol;
        ushort4 o;
        o.x = f2b(sigm(sp[0]));
        o.y = f2b(sigm(sp[SS]));
        o.z = f2b(sigm(sp[2 * SS]));
        o.w = f2b(sigm(sp[3 * SS]));
        *(ushort4*)(tb + (mi * 2 + (ni >> 1)) * 512 + (ni & 1) * 4) = o;
      }
      continue;
    }

    // ---- 128-row projection tile (r13 body) ----
    long row0 = (long)unit * 128;
    const float* src;
    u16* dst;
    if (row0 < (long)BB * SS) { src = tgt + row0 * DD; dst = qb + row0 * DD; }
    else { src = memin + (row0 - (long)BB * SS) * DD; dst = kb + (row0 - (long)BB * SS) * DD; }

    for (int p = 0; p < 16; ++p) {
      int r = p * 8 + (tid >> 5);
      int c4 = (tid & 31) * 4;
      float4 v = *(const float4*)(src + r * DD + c4);
      *(u32*)&sA[r * RS + c4] = packb2(v.x, v.y);
      *(u32*)&sA[r * RS + c4 + 2] = packb2(v.z, v.w);
      float4 w = *(const float4*)(w1 + r * DD + c4);
      *(u32*)&sB[r * RS + c4] = packb2(w.x, w.y);
      *(u32*)&sB[r * RS + c4 + 2] = packb2(w.z, w.w);
    }
    if (tid < 128) sq[tid] = 0.f;
    __syncthreads();

    floatx4 acc[4][4];
    for (int mi = 0; mi < 4; ++mi)
      for (int ni = 0; ni < 4; ++ni) acc[mi][ni] = (floatx4){0.f, 0.f, 0.f, 0.f};

    for (int kc = 0; kc < 4; ++kc) {
      int k0 = kc * 32 + lg * 8;
      short8 af[4], bfr[4];
      for (int mi = 0; mi < 4; ++mi)
        af[mi] = *(const short8*)&sA[(wr * 64 + mi * 16 + l15) * RS + k0];
      for (int ni = 0; ni < 4; ++ni)
        bfr[ni] = *(const short8*)&sB[(wc * 64 + ni * 16 + l15) * RS + k0];
      for (int mi = 0; mi < 4; ++mi)
        for (int ni = 0; ni < 4; ++ni)
          acc[mi][ni] = __builtin_amdgcn_mfma_f32_16x16x32_bf16(af[mi], bfr[ni], acc[mi][ni], 0, 0, 0);
    }

    float bvals[4];
    for (int ni = 0; ni < 4; ++ni) bvals[ni] = b1[wc * 64 + ni * 16 + l15];
    for (int mi = 0; mi < 4; ++mi)
      for (int r = 0; r < 4; ++r) {
        float s = 0.f;
        for (int ni = 0; ni < 4; ++ni) {
          float v = acc[mi][ni][r] + bvals[ni];
          acc[mi][ni][r] = v;
          s += v * v;
        }
        s += __shfl_xor(s, 1); s += __shfl_xor(s, 2);
        s += __shfl_xor(s, 4); s += __shfl_xor(s, 8);
        if (l15 == 0) atomicAdd(&sq[wr * 64 + mi * 16 + lg * 4 + r], s);
      }
    __syncthreads();

    for (int mi = 0; mi < 4; ++mi)
      for (int r = 0; r < 4; ++r) {
        int row = wr * 64 + mi * 16 + lg * 4 + r;
        float scale = 1.f / fmaxf(sqrtf(sq[row]), 1e-12f);
        for (int ni = 0; ni < 4; ++ni)
          sA[row * RS + wc * 64 + ni * 16 + l15] = f2b(acc[mi][ni][r] * scale);
      }
    __syncthreads();
    for (int p = 0; p < 8; ++p) {
      int r = p * 16 + (tid >> 4);
      int c8 = (tid & 15) * 8;
      *(uint4*)(dst + r * DD + c8) = *(const uint4*)&sA[r * RS + c8];
    }
  }
}

// ---------------- K2: one 128x128 attn tile pair per block (r10/r12/r13 verbatim) ----------------
__global__ __launch_bounds__(256, 4) void k_attn(const u16* __restrict__ qb,
                                                 const u16* __restrict__ kb,
                                                 const u16* __restrict__ gT2,
                                                 u32* __restrict__ m1u, u32* __restrict__ m2u) {
  __shared__ u16 sK[128 * RS];
  __shared__ float scmax[2][128];
  __shared__ float srmax[2][128];
  int tid = threadIdx.x;
  int n = blockIdx.x;  // 5408 = 8 XCDs * 169 tiles * 4 batches
  int m = n >> 3;      // 0..675
  int r2 = m >> 2;     // tile index, adjacent across the 4 batches
  int b = (n & 7) * 4 + (m & 3);
  int sy = r2 / 13, tx = r2 - sy * 13;
  int s0 = min(sy * 128, SS - 128);  // edge tiles clamp-overlap; max is idempotent
  int t0 = min(tx * 128, SS - 128);
  int lane = tid & 63, wv = tid >> 6;
  int wr = wv >> 1, wc = wv & 1;
  int l15 = lane & 15, lg = lane >> 4;
  const size_t base = (size_t)b * SS * DD;
  const u16* qp = qb + base + (size_t)(s0 + wr * 64 + l15) * DD + lg * 8;

  // K tile -> LDS
  {
    int rr0 = tid >> 4;
    int c8 = (tid & 15) * 8;
    const u16* kp = kb + base + (size_t)(t0 + rr0) * DD + c8;
    u16* sp = &sK[rr0 * RS + c8];
    for (int p = 0; p < 8; ++p)
      *(uint4*)(sp + p * 16 * RS) = *(const uint4*)(kp + (size_t)p * 16 * DD);
  }
  // first Q slice (kc=0)
  short8 qsA[4], qsB[4];
  for (int mi = 0; mi < 4; ++mi) qsA[mi] = *(const short8*)(qp + mi * 16 * DD);
  __syncthreads();

  floatx4 acc[4][4];
  for (int mi = 0; mi < 4; ++mi)
    for (int ni = 0; ni < 4; ++ni) acc[mi][ni] = (floatx4){0.f, 0.f, 0.f, 0.f};

#define QKSTEP(KC, CUR, NXT, PRE)                                                     \
  {                                                                                   \
    if (PRE)                                                                          \
      for (int mi = 0; mi < 4; ++mi)                                                  \
        NXT[mi] = *(const short8*)(qp + mi * 16 * DD + ((KC) + 1) * 32);              \
    int k0 = (KC)*32 + lg * 8;                                                        \
    short8 bfr[4];                                                                    \
    for (int ni = 0; ni < 4; ++ni)                                                    \
      bfr[ni] = *(const short8*)&sK[(wc * 64 + ni * 16 + l15) * RS + k0];             \
    for (int mi = 0; mi < 4; ++mi)                                                    \
      for (int ni = 0; ni < 4; ++ni)                                                  \
        acc[mi][ni] = __builtin_amdgcn_mfma_f32_16x16x32_bf16(CUR[mi], bfr[ni],       \
                                                              acc[mi][ni], 0, 0, 0);  \
  }
  QKSTEP(0, qsA, qsB, 1)
  QKSTEP(1, qsB, qsA, 1)
  QKSTEP(2, qsA, qsB, 1)
  QKSTEP(3, qsB, qsA, 0)
#undef QKSTEP

  // paired gate loads: 8 x uint4 (1KB/wave each), after MFMA so regs don't overlap qs/bfr
  uint4 g4[8];
  {
    const u16* gbase = gT2 + (size_t)r2 * 16384 + wv * 4096 + lane * 8;
    for (int p = 0; p < 8; ++p) g4[p] = *(const uint4*)(gbase + p * 512);
  }

  // gate multiply + row/col max
  float rmax[4][4];
  for (int mi = 0; mi < 4; ++mi)
    for (int r = 0; r < 4; ++r) rmax[mi][r] = -1e30f;
  float cmax[4];
  for (int ni = 0; ni < 4; ++ni) cmax[ni] = -1e30f;

  for (int mi = 0; mi < 4; ++mi)
    for (int ni = 0; ni < 4; ++ni) {
      uint4 pg = g4[mi * 2 + (ni >> 1)];
      u32 lo = (ni & 1) ? pg.z : pg.x;  // bf16 pair for r=0,1
      u32 hi = (ni & 1) ? pg.w : pg.y;  // bf16 pair for r=2,3
      float v0 = acc[mi][ni][0] * __uint_as_float(lo << 16);
      float v1 = acc[mi][ni][1] * __uint_as_float(lo & 0xffff0000u);
      float v2 = acc[mi][ni][2] * __uint_as_float(hi << 16);
      float v3 = acc[mi][ni][3] * __uint_as_float(hi & 0xffff0000u);
      rmax[mi][0] = fmaxf(rmax[mi][0], v0);
      rmax[mi][1] = fmaxf(rmax[mi][1], v1);
      rmax[mi][2] = fmaxf(rmax[mi][2], v2);
      rmax[mi][3] = fmaxf(rmax[mi][3], v3);
      cmax[ni] = fmaxf(cmax[ni], fmaxf(fmaxf(v0, v1), fmaxf(v2, v3)));
    }

  // column max: reduce over lg (rows) within wave, then across wr via LDS
  for (int ni = 0; ni < 4; ++ni) {
    cmax[ni] = fmaxf(cmax[ni], __shfl_xor(cmax[ni], 16));
    cmax[ni] = fmaxf(cmax[ni], __shfl_xor(cmax[ni], 32));
  }
  if (lane < 16)
    for (int ni = 0; ni < 4; ++ni) scmax[wr][wc * 64 + ni * 16 + lane] = cmax[ni];

  // row max: reduce over l15 (cols) within wave, then across wc via LDS
  for (int mi = 0; mi < 4; ++mi)
    for (int r = 0; r < 4; ++r) {
      float v = rmax[mi][r];
      v = fmaxf(v, __shfl_xor(v, 1));
      v = fmaxf(v, __shfl_xor(v, 2));
      v = fmaxf(v, __shfl_xor(v, 4));
      v = fmaxf(v, __shfl_xor(v, 8));
      if (l15 == 0) srmax[wc][wr * 64 + mi * 16 + lg * 4 + r] = v;
    }
  __syncthreads();

  if (tid < 128) {
    float v = fmaxf(scmax[0][tid], scmax[1][tid]);
    atomicMax(&m1u[b * SS + t0 + tid], encf(v));
  } else {
    int i2 = tid - 128;
    float v = fmaxf(srmax[0][i2], srmax[1][i2]);
    atomicMax(&m2u[b * SS + s0 + i2], encf(v));
  }
}

// ---------------- K3b: partial(BN1(x) @ w2^T), BN1 fused, 16-way split, GRID-STRIDED ----------------
__global__ __launch_bounds__(256) void k_gemm2(const u32* __restrict__ m1u,
                                               const u32* __restrict__ m2u,
                                               const float* __restrict__ g1,
                                               const float* __restrict__ be1,
                                               const float* __restrict__ w2,
                                               float* __restrict__ hacc) {
  int tid = threadIdx.x;
  int lane = tid & 63, wv = tid >> 6;
  int c_sub = lane & 15, bq = lane >> 4;
  const float bnc = rsqrtf(1.f + 1e-5f);
  const float4 z4 = {0.f, 0.f, 0.f, 0.f};

  for (int u = blockIdx.x; u < 1024; u += 512) {  // 512 blocks x 2 units
    int f0 = (u & 63) * 32 + wv * 8;
    int cs = u >> 6;  // 0..15, 200 cols each
    int cr0 = cs * 200;
    const u32* msrc = (cs < 8) ? m1u : m2u;
    int mcol0 = cr0 - ((cs < 8) ? 0 : SS);
    float acc[8][8];
    for (int a = 0; a < 8; ++a)
      for (int c = 0; c < 8; ++c) acc[a][c] = 0.f;
    for (int it = 0; it < 4; ++it) {
      int coff = it * 64 + c_sub * 4;
      bool ok = coff < 200;
      int cg = cr0 + coff;
      float4 w4[8], x4[8];
      float4 gv = ok ? *(const float4*)(g1 + cg) : z4;
      float4 bv = ok ? *(const float4*)(be1 + cg) : z4;
      gv.x *= bnc; gv.y *= bnc; gv.z *= bnc; gv.w *= bnc;
      for (int jf = 0; jf < 8; ++jf)
        w4[jf] = ok ? *(const float4*)(w2 + (size_t)(f0 + jf) * S2N + cg) : z4;
      for (int j = 0; j < 8; ++j) {
        if (ok) {
          uint4 e = *(const uint4*)(msrc + (size_t)(bq * 8 + j) * SS + mcol0 + coff);
          x4[j].x = decf(e.x) * gv.x + bv.x;
          x4[j].y = decf(e.y) * gv.y + bv.y;
          x4[j].z = decf(e.z) * gv.z + bv.z;
          x4[j].w = decf(e.w) * gv.w + bv.w;
        } else {
          x4[j] = z4;
        }
      }
      for (int jf = 0; jf < 8; ++jf)
        for (int j = 0; j < 8; ++j) {
          float a = acc[jf][j];
          a = fmaf(w4[jf].x, x4[j].x, a);
          a = fmaf(w4[jf].y, x4[j].y, a);
          a = fmaf(w4[jf].z, x4[j].z, a);
          a = fmaf(w4[jf].w, x4[j].w, a);
          acc[jf][j] = a;
        }
    }
    for (int jf = 0; jf < 8; ++jf)
      for (int j = 0; j < 8; ++j) {
        float v = acc[jf][j];
        v += __shfl_xor(v, 1); v += __shfl_xor(v, 2);
        v += __shfl_xor(v, 4); v += __shfl_xor(v, 8);
        acc[jf][j] = v;
      }
    if ((lane & 15) == 0) {
      for (int jf = 0; jf < 8; ++jf)
        for (int j = 0; j < 8; ++j) {
          int b = bq * 8 + j;
          hacc[((size_t)cs * BB + b) * DFFN + f0 + jf] = acc[jf][j];
        }
    }
  }
}

// ---------------- K3c: BN2 + relu + dot w3 + BN3 (512 threads, float4, 16 slices) ----------------
__global__ __launch_bounds__(512) void k_final(const float* __restrict__ hacc,
                                               const float* __restrict__ b2,
                                               const float* __restrict__ g2,
                                               const float* __restrict__ be2,
                                               const float* __restrict__ w3,
                                               const float* __restrict__ b3,
                                               const float* __restrict__ g3,
                                               const float* __restrict__ be3,
                                               float* __restrict__ out) {
  __shared__ float wsum[8];
  int b = blockIdx.x;
  int tid = threadIdx.x;
  float bnc = rsqrtf(1.f + 1e-5f);
  int f4i = tid;  // one float4 (4 f) per thread: 512*4 = 2048
  float4 s4 = *(const float4*)(b2 + f4i * 4);
  for (int cs = 0; cs < 16; ++cs) {
    float4 h = *(const float4*)(hacc + ((size_t)cs * BB + b) * DFFN + f4i * 4);
    s4.x += h.x; s4.y += h.y; s4.z += h.z; s4.w += h.w;
  }
  float4 gv = *(const float4*)(g2 + f4i * 4);
  float4 bv = *(const float4*)(be2 + f4i * 4);
  float4 w4 = *(const float4*)(w3 + f4i * 4);
  float part = 0.f;
  part += fmaxf(s4.x * (gv.x * bnc) + bv.x, 0.f) * w4.x;
  part += fmaxf(s4.y * (gv.y * bnc) + bv.y, 0.f) * w4.y;
  part += fmaxf(s4.z * (gv.z * bnc) + bv.z, 0.f) * w4.z;
  part += fmaxf(s4.w * (gv.w * bnc) + bv.w, 0.f) * w4.w;
  for (int m = 1; m < 64; m <<= 1) part += __shfl_xor(part, m);
  if ((tid & 63) == 0) wsum[tid >> 6] = part;
  __syncthreads();
  if (tid == 0) {
    float tot = b3[0];
    for (int wq = 0; wq < 8; ++wq) tot += wsum[wq];
    out[b] = tot * (g3[0] * bnc) + be3[0];
  }
}

extern "C" void kernel_launch(void* const* d_in, const int* in_sizes, int n_in,
                              void* d_out, int out_size, void* d_ws, size_t ws_size,
                              hipStream_t stream) {
  const float* tgt = (const float*)d_in[0];
  const float* memin = (const float*)d_in[1];
  const float* se = (const float*)d_in[2];
  const float* w1 = (const float*)d_in[3];
  const float* b1 = (const float*)d_in[4];
  const float* g1 = (const float*)d_in[5];
  const float* be1 = (const float*)d_in[6];
  const float* w2 = (const float*)d_in[7];
  const float* b2 = (const float*)d_in[8];
  const float* g2 = (const float*)d_in[9];
  const float* be2 = (const float*)d_in[10];
  const float* w3 = (const float*)d_in[11];
  const float* b3 = (const float*)d_in[12];
  const float* g3 = (const float*)d_in[13];
  const float* be3 = (const float*)d_in[14];
  float* out = (float*)d_out;

  char* ws = (char*)d_ws;
  const size_t OFF_GT = 0;                        // tiled bf16 gate: 169*16384*2 = 5,537,792
  const size_t OFF_QB = 5537792;                  // 13,107,200
  const size_t OFF_KB = OFF_QB + 13107200;
  const size_t OFF_M1 = OFF_KB + 13107200;        // 204,800
  const size_t OFF_M2 = OFF_M1 + 204800;
  const size_t OFF_HA = OFF_M2 + 204800;          // 16*32*2048*4 = 4,194,304
  const size_t NEEDED = OFF_HA + 4194304;
  if (ws_size < NEEDED) return;  // clean validation failure rather than OOB

  u16* gT2 = (u16*)(ws + OFF_GT);
  u16* qb = (u16*)(ws + OFF_QB);
  u16* kb = (u16*)(ws + OFF_KB);
  u32* m1u = (u32*)(ws + OFF_M1);
  u32* m2u = (u32*)(ws + OFF_M2);
  float* hacc = (float*)(ws + OFF_HA);

  k_prep<<<512, 256, 0, stream>>>(tgt, memin, w1, b1, se, qb, kb, gT2, m1u, m2u);
  k_attn<<<5408, 256, 0, stream>>>(qb, kb, gT2, m1u, m2u);
  k_gemm2<<<512, 256, 0, stream>>>(m1u, m2u, g1, be1, w2, hacc);
  k_final<<<32, 512, 0, stream>>>(hacc, b2, g2, be2, w3, b3, g3, be3, out);
}

// Round 18
// 143.334 us; speedup vs baseline: 1.0713x; 1.0713x over previous
//
#include <hip/hip_runtime.h>
#include <hip/hip_bf16.h>

#define BB 32
#define SS 1600
#define DD 128
#define DFFN 2048
#define S2N 3200
#define RS 136  // LDS row stride in bf16 elems (128 + 8 pad)

typedef __attribute__((ext_vector_type(8))) short short8;
typedef __attribute__((ext_vector_type(4))) float floatx4;
typedef unsigned int u32;
typedef unsigned short u16;

__device__ __forceinline__ u32 encf(float f) {
  u32 u = __float_as_uint(f);
  return (u & 0x80000000u) ? ~u : (u | 0x80000000u);
}
__device__ __forceinline__ float decf(u32 e) {
  u32 u = (e & 0x80000000u) ? (e & 0x7fffffffu) : ~e;
  return __uint_as_float(u);
}
// fast RNE fp32->bf16 (finite data; matches library rounding)
__device__ __forceinline__ u16 f2b(float x) {
  u32 u = __float_as_uint(x);
  return (u16)((u + 0x7FFFu + ((u >> 16) & 1u)) >> 16);
}
__device__ __forceinline__ u32 packb2(float lo, float hi) {
  return (u32)f2b(lo) | ((u32)f2b(hi) << 16);
}
__device__ __forceinline__ float sigm(float x) { return 1.f / (1.f + __expf(-x)); }

// ---------------- K1: fused prep (r12 verbatim) ----------------
// blocks [0,800): q/k projection + l2norm (bf16 MFMA; w1 staged once->LDS sB)
// blocks [800,1476): gate tiles (PAIRED fragment layout) + m1u/m2u init
__global__ __launch_bounds__(256) void k_prep(const float* __restrict__ tgt,
                                              const float* __restrict__ memin,
                                              const float* __restrict__ w1,
                                              const float* __restrict__ b1,
                                              const float* __restrict__ se,
                                              u16* __restrict__ qb, u16* __restrict__ kb,
                                              u16* __restrict__ gT2,
                                              u32* __restrict__ m1u, u32* __restrict__ m2u) {
  __shared__ u16 sA[128 * RS];
  __shared__ u16 sB[128 * RS];
  __shared__ float sq[128];
  int tid = threadIdx.x;
  int lane = tid & 63, wv = tid >> 6;
  int wr = wv >> 1, wc = wv & 1;
  int l15 = lane & 15, lg = lane >> 4;

  if (blockIdx.x >= 800) {  // ---- gate-tile build + max-array init ----
    int bid = blockIdx.x - 800;       // 0..675
    int ii = bid * 256 + tid;
    if (ii < BB * SS) {  // 0 encodes "below every finite float"
      m1u[ii] = 0u;
      m2u[ii] = 0u;
    }
    int r2 = bid >> 2, mi = bid & 3;  // quarter-tile per block
    int sy = r2 / 13, tx = r2 - sy * 13;
    int s0 = min(sy * 128, SS - 128);
    int t0 = min(tx * 128, SS - 128);
    int srow = s0 + wr * 64 + mi * 16 + lg * 4;
    u16* tb = gT2 + (size_t)r2 * 16384 + wv * 4096 + lane * 8;
    for (int ni = 0; ni < 4; ++ni) {
      int tcol = t0 + wc * 64 + ni * 16 + l15;
      const float* sp = se + (size_t)srow * SS + tcol;
      ushort4 o;
      o.x = f2b(sigm(sp[0]));
      o.y = f2b(sigm(sp[SS]));
      o.z = f2b(sigm(sp[2 * SS]));
      o.w = f2b(sigm(sp[3 * SS]));
      *(ushort4*)(tb + (mi * 2 + (ni >> 1)) * 512 + (ni & 1) * 4) = o;
    }
    return;
  }

  // ---- projection ----
  long row0 = (long)blockIdx.x * 128;
  const float* src;
  u16* dst;
  if (row0 < (long)BB * SS) { src = tgt + row0 * DD; dst = qb + row0 * DD; }
  else { src = memin + (row0 - (long)BB * SS) * DD; dst = kb + (row0 - (long)BB * SS) * DD; }

  for (int p = 0; p < 16; ++p) {
    int r = p * 8 + (tid >> 5);
    int c4 = (tid & 31) * 4;
    float4 v = *(const float4*)(src + r * DD + c4);
    *(u32*)&sA[r * RS + c4] = packb2(v.x, v.y);
    *(u32*)&sA[r * RS + c4 + 2] = packb2(v.z, v.w);
    float4 w = *(const float4*)(w1 + r * DD + c4);
    *(u32*)&sB[r * RS + c4] = packb2(w.x, w.y);
    *(u32*)&sB[r * RS + c4 + 2] = packb2(w.z, w.w);
  }
  if (tid < 128) sq[tid] = 0.f;
  __syncthreads();

  floatx4 acc[4][4];
  for (int mi = 0; mi < 4; ++mi)
    for (int ni = 0; ni < 4; ++ni) acc[mi][ni] = (floatx4){0.f, 0.f, 0.f, 0.f};

  for (int kc = 0; kc < 4; ++kc) {
    int k0 = kc * 32 + lg * 8;
    short8 af[4], bfr[4];
    for (int mi = 0; mi < 4; ++mi) af[mi] = *(const short8*)&sA[(wr * 64 + mi * 16 + l15) * RS + k0];
    for (int ni = 0; ni < 4; ++ni) bfr[ni] = *(const short8*)&sB[(wc * 64 + ni * 16 + l15) * RS + k0];
    for (int mi = 0; mi < 4; ++mi)
      for (int ni = 0; ni < 4; ++ni)
        acc[mi][ni] = __builtin_amdgcn_mfma_f32_16x16x32_bf16(af[mi], bfr[ni], acc[mi][ni], 0, 0, 0);
  }

  float bvals[4];
  for (int ni = 0; ni < 4; ++ni) bvals[ni] = b1[wc * 64 + ni * 16 + l15];
  for (int mi = 0; mi < 4; ++mi)
    for (int r = 0; r < 4; ++r) {
      float s = 0.f;
      for (int ni = 0; ni < 4; ++ni) {
        float v = acc[mi][ni][r] + bvals[ni];
        acc[mi][ni][r] = v;
        s += v * v;
      }
      s += __shfl_xor(s, 1); s += __shfl_xor(s, 2);
      s += __shfl_xor(s, 4); s += __shfl_xor(s, 8);
      if (l15 == 0) atomicAdd(&sq[wr * 64 + mi * 16 + lg * 4 + r], s);
    }
  __syncthreads();

  for (int mi = 0; mi < 4; ++mi)
    for (int r = 0; r < 4; ++r) {
      int row = wr * 64 + mi * 16 + lg * 4 + r;
      float scale = 1.f / fmaxf(sqrtf(sq[row]), 1e-12f);
      for (int ni = 0; ni < 4; ++ni)
        sA[row * RS + wc * 64 + ni * 16 + l15] = f2b(acc[mi][ni][r] * scale);
    }
  __syncthreads();
  for (int p = 0; p < 8; ++p) {
    int r = p * 16 + (tid >> 4);
    int c8 = (tid & 15) * 8;
    *(uint4*)(dst + r * DD + c8) = *(const uint4*)&sA[r * RS + c8];
  }
}

// ---------------- K2: one 128x128 attn tile pair per block (r12 + T5 setprio) ----------------
__global__ __launch_bounds__(256, 4) void k_attn(const u16* __restrict__ qb,
                                                 const u16* __restrict__ kb,
                                                 const u16* __restrict__ gT2,
                                                 u32* __restrict__ m1u, u32* __restrict__ m2u) {
  __shared__ u16 sK[128 * RS];
  __shared__ float scmax[2][128];
  __shared__ float srmax[2][128];
  int tid = threadIdx.x;
  int n = blockIdx.x;  // 5408 = 8 XCDs * 169 tiles * 4 batches
  int m = n >> 3;      // 0..675
  int r2 = m >> 2;     // tile index, adjacent across the 4 batches
  int b = (n & 7) * 4 + (m & 3);
  int sy = r2 / 13, tx = r2 - sy * 13;
  int s0 = min(sy * 128, SS - 128);  // edge tiles clamp-overlap; max is idempotent
  int t0 = min(tx * 128, SS - 128);
  int lane = tid & 63, wv = tid >> 6;
  int wr = wv >> 1, wc = wv & 1;
  int l15 = lane & 15, lg = lane >> 4;
  const size_t base = (size_t)b * SS * DD;
  const u16* qp = qb + base + (size_t)(s0 + wr * 64 + l15) * DD + lg * 8;

  // K tile -> LDS
  {
    int rr0 = tid >> 4;
    int c8 = (tid & 15) * 8;
    const u16* kp = kb + base + (size_t)(t0 + rr0) * DD + c8;
    u16* sp = &sK[rr0 * RS + c8];
    for (int p = 0; p < 8; ++p)
      *(uint4*)(sp + p * 16 * RS) = *(const uint4*)(kp + (size_t)p * 16 * DD);
  }
  // first Q slice (kc=0)
  short8 qsA[4], qsB[4];
  for (int mi = 0; mi < 4; ++mi) qsA[mi] = *(const short8*)(qp + mi * 16 * DD);
  __syncthreads();

  floatx4 acc[4][4];
  for (int mi = 0; mi < 4; ++mi)
    for (int ni = 0; ni < 4; ++ni) acc[mi][ni] = (floatx4){0.f, 0.f, 0.f, 0.f};

  // T5: bias CU scheduler toward this wave's MFMA cluster; blocks on a CU are at
  // different phases (4 independent blocks/CU), the regime where setprio measured +.
  __builtin_amdgcn_s_setprio(1);
#define QKSTEP(KC, CUR, NXT, PRE)                                                     \
  {                                                                                   \
    if (PRE)                                                                          \
      for (int mi = 0; mi < 4; ++mi)                                                  \
        NXT[mi] = *(const short8*)(qp + mi * 16 * DD + ((KC) + 1) * 32);              \
    int k0 = (KC)*32 + lg * 8;                                                        \
    short8 bfr[4];                                                                    \
    for (int ni = 0; ni < 4; ++ni)                                                    \
      bfr[ni] = *(const short8*)&sK[(wc * 64 + ni * 16 + l15) * RS + k0];             \
    for (int mi = 0; mi < 4; ++mi)                                                    \
      for (int ni = 0; ni < 4; ++ni)                                                  \
        acc[mi][ni] = __builtin_amdgcn_mfma_f32_16x16x32_bf16(CUR[mi], bfr[ni],       \
                                                              acc[mi][ni], 0, 0, 0);  \
  }
  QKSTEP(0, qsA, qsB, 1)
  QKSTEP(1, qsB, qsA, 1)
  QKSTEP(2, qsA, qsB, 1)
  QKSTEP(3, qsB, qsA, 0)
#undef QKSTEP
  __builtin_amdgcn_s_setprio(0);

  // paired gate loads: 8 x uint4 (1KB/wave each), after MFMA so regs don't overlap qs/bfr
  uint4 g4[8];
  {
    const u16* gbase = gT2 + (size_t)r2 * 16384 + wv * 4096 + lane * 8;
    for (int p = 0; p < 8; ++p) g4[p] = *(const uint4*)(gbase + p * 512);
  }

  // gate multiply + row/col max
  float rmax[4][4];
  for (int mi = 0; mi < 4; ++mi)
    for (int r = 0; r < 4; ++r) rmax[mi][r] = -1e30f;
  float cmax[4];
  for (int ni = 0; ni < 4; ++ni) cmax[ni] = -1e30f;

  for (int mi = 0; mi < 4; ++mi)
    for (int ni = 0; ni < 4; ++ni) {
      uint4 pg = g4[mi * 2 + (ni >> 1)];
      u32 lo = (ni & 1) ? pg.z : pg.x;  // bf16 pair for r=0,1
      u32 hi = (ni & 1) ? pg.w : pg.y;  // bf16 pair for r=2,3
      float v0 = acc[mi][ni][0] * __uint_as_float(lo << 16);
      float v1 = acc[mi][ni][1] * __uint_as_float(lo & 0xffff0000u);
      float v2 = acc[mi][ni][2] * __uint_as_float(hi << 16);
      float v3 = acc[mi][ni][3] * __uint_as_float(hi & 0xffff0000u);
      rmax[mi][0] = fmaxf(rmax[mi][0], v0);
      rmax[mi][1] = fmaxf(rmax[mi][1], v1);
      rmax[mi][2] = fmaxf(rmax[mi][2], v2);
      rmax[mi][3] = fmaxf(rmax[mi][3], v3);
      cmax[ni] = fmaxf(cmax[ni], fmaxf(fmaxf(v0, v1), fmaxf(v2, v3)));
    }

  // column max: reduce over lg (rows) within wave, then across wr via LDS
  for (int ni = 0; ni < 4; ++ni) {
    cmax[ni] = fmaxf(cmax[ni], __shfl_xor(cmax[ni], 16));
    cmax[ni] = fmaxf(cmax[ni], __shfl_xor(cmax[ni], 32));
  }
  if (lane < 16)
    for (int ni = 0; ni < 4; ++ni) scmax[wr][wc * 64 + ni * 16 + lane] = cmax[ni];

  // row max: reduce over l15 (cols) within wave, then across wc via LDS
  for (int mi = 0; mi < 4; ++mi)
    for (int r = 0; r < 4; ++r) {
      float v = rmax[mi][r];
      v = fmaxf(v, __shfl_xor(v, 1));
      v = fmaxf(v, __shfl_xor(v, 2));
      v = fmaxf(v, __shfl_xor(v, 4));
      v = fmaxf(v, __shfl_xor(v, 8));
      if (l15 == 0) srmax[wc][wr * 64 + mi * 16 + lg * 4 + r] = v;
    }
  __syncthreads();

  if (tid < 128) {
    float v = fmaxf(scmax[0][tid], scmax[1][tid]);
    atomicMax(&m1u[b * SS + t0 + tid], encf(v));
  } else {
    int i2 = tid - 128;
    float v = fmaxf(srmax[0][i2], srmax[1][i2]);
    atomicMax(&m2u[b * SS + s0 + i2], encf(v));
  }
}

// ---------------- K3b: hacc[cs][b][f] = partial(BN1(x) @ w2^T), BN1 fused, 8-way split ----------------
__global__ __launch_bounds__(256) void k_gemm2(const u32* __restrict__ m1u,
                                               const u32* __restrict__ m2u,
                                               const float* __restrict__ g1,
                                               const float* __restrict__ be1,
                                               const float* __restrict__ w2,
                                               float* __restrict__ hacc) {
  int tid = threadIdx.x;
  int lane = tid & 63, wv = tid >> 6;
  int f0 = blockIdx.x * 32 + wv * 8;
  int cs = blockIdx.y;
  int cr0 = cs * 400;
  const u32* msrc = (cs < 4) ? m1u : m2u;
  int mcol0 = cr0 - ((cs < 4) ? 0 : SS);
  int c_sub = lane & 15, bq = lane >> 4;
  const float bnc = rsqrtf(1.f + 1e-5f);
  float acc[8][8];
  for (int a = 0; a < 8; ++a)
    for (int c = 0; c < 8; ++c) acc[a][c] = 0.f;
  const float4 z4 = {0.f, 0.f, 0.f, 0.f};
  for (int it = 0; it < 7; ++it) {
    int coff = it * 64 + c_sub * 4;
    bool ok = coff < 400;
    int cg = cr0 + coff;
    float4 w4[8], x4[8];
    float4 gv = ok ? *(const float4*)(g1 + cg) : z4;
    float4 bv = ok ? *(const float4*)(be1 + cg) : z4;
    gv.x *= bnc; gv.y *= bnc; gv.z *= bnc; gv.w *= bnc;
    for (int jf = 0; jf < 8; ++jf)
      w4[jf] = ok ? *(const float4*)(w2 + (size_t)(f0 + jf) * S2N + cg) : z4;
    for (int j = 0; j < 8; ++j) {
      if (ok) {
        uint4 e = *(const uint4*)(msrc + (size_t)(bq * 8 + j) * SS + mcol0 + coff);
        x4[j].x = decf(e.x) * gv.x + bv.x;
        x4[j].y = decf(e.y) * gv.y + bv.y;
        x4[j].z = decf(e.z) * gv.z + bv.z;
        x4[j].w = decf(e.w) * gv.w + bv.w;
      } else {
        x4[j] = z4;
      }
    }
    for (int jf = 0; jf < 8; ++jf)
      for (int j = 0; j < 8; ++j) {
        float a = acc[jf][j];
        a = fmaf(w4[jf].x, x4[j].x, a);
        a = fmaf(w4[jf].y, x4[j].y, a);
        a = fmaf(w4[jf].z, x4[j].z, a);
        a = fmaf(w4[jf].w, x4[j].w, a);
        acc[jf][j] = a;
      }
  }
  for (int jf = 0; jf < 8; ++jf)
    for (int j = 0; j < 8; ++j) {
      float v = acc[jf][j];
      v += __shfl_xor(v, 1); v += __shfl_xor(v, 2);
      v += __shfl_xor(v, 4); v += __shfl_xor(v, 8);
      acc[jf][j] = v;
    }
  if ((lane & 15) == 0) {
    for (int jf = 0; jf < 8; ++jf)
      for (int j = 0; j < 8; ++j) {
        int b = bq * 8 + j;
        hacc[((size_t)cs * BB + b) * DFFN + f0 + jf] = acc[jf][j];
      }
  }
}

// ---------------- K3c: BN2 + relu + dot w3 + BN3 ----------------
__global__ __launch_bounds__(256) void k_final(const float* __restrict__ hacc,
                                               const float* __restrict__ b2,
                                               const float* __restrict__ g2,
                                               const float* __restrict__ be2,
                                               const float* __restrict__ w3,
                                               const float* __restrict__ b3,
                                               const float* __restrict__ g3,
                                               const float* __restrict__ be3,
                                               float* __restrict__ out) {
  __shared__ float wsum[4];
  int b = blockIdx.x;
  int tid = threadIdx.x;
  float bnc = rsqrtf(1.f + 1e-5f);
  float part = 0.f;
  for (int f = tid; f < DFFN; f += 256) {
    float s = b2[f];
    for (int cs = 0; cs < 8; ++cs) s += hacc[((size_t)cs * BB + b) * DFFN + f];
    s = s * (g2[f] * bnc) + be2[f];
    s = fmaxf(s, 0.f);
    part += s * w3[f];
  }
  for (int m = 1; m < 64; m <<= 1) part += __shfl_xor(part, m);
  if ((tid & 63) == 0) wsum[tid >> 6] = part;
  __syncthreads();
  if (tid == 0) {
    float tot = wsum[0] + wsum[1] + wsum[2] + wsum[3] + b3[0];
    out[b] = tot * (g3[0] * bnc) + be3[0];
  }
}

extern "C" void kernel_launch(void* const* d_in, const int* in_sizes, int n_in,
                              void* d_out, int out_size, void* d_ws, size_t ws_size,
                              hipStream_t stream) {
  const float* tgt = (const float*)d_in[0];
  const float* memin = (const float*)d_in[1];
  const float* se = (const float*)d_in[2];
  const float* w1 = (const float*)d_in[3];
  const float* b1 = (const float*)d_in[4];
  const float* g1 = (const float*)d_in[5];
  const float* be1 = (const float*)d_in[6];
  const float* w2 = (const float*)d_in[7];
  const float* b2 = (const float*)d_in[8];
  const float* g2 = (const float*)d_in[9];
  const float* be2 = (const float*)d_in[10];
  const float* w3 = (const float*)d_in[11];
  const float* b3 = (const float*)d_in[12];
  const float* g3 = (const float*)d_in[13];
  const float* be3 = (const float*)d_in[14];
  float* out = (float*)d_out;

  char* ws = (char*)d_ws;
  const size_t OFF_GT = 0;                        // tiled bf16 gate: 169*16384*2 = 5,537,792
  const size_t OFF_QB = 5537792;                  // 13,107,200
  const size_t OFF_KB = OFF_QB + 13107200;
  const size_t OFF_M1 = OFF_KB + 13107200;        // 204,800
  const size_t OFF_M2 = OFF_M1 + 204800;
  const size_t OFF_HA = OFF_M2 + 204800;          // 8*32*2048*4 = 2,097,152
  const size_t NEEDED = OFF_HA + 2097152;
  if (ws_size < NEEDED) return;  // clean validation failure rather than OOB

  u16* gT2 = (u16*)(ws + OFF_GT);
  u16* qb = (u16*)(ws + OFF_QB);
  u16* kb = (u16*)(ws + OFF_KB);
  u32* m1u = (u32*)(ws + OFF_M1);
  u32* m2u = (u32*)(ws + OFF_M2);
  float* hacc = (float*)(ws + OFF_HA);

  k_prep<<<1476, 256, 0, stream>>>(tgt, memin, w1, b1, se, qb, kb, gT2, m1u, m2u);
  k_attn<<<5408, 256, 0, stream>>>(qb, kb, gT2, m1u, m2u);
  k_gemm2<<<dim3(64, 8), 256, 0, stream>>>(m1u, m2u, g1, be1, w2, hacc);
  k_final<<<32, 256, 0, stream>>>(hacc, b2, g2, be2, w3, b3, g3, be3, out);
}

// Round 19
// 134.692 us; speedup vs baseline: 1.1400x; 1.0642x over previous
//
#include <hip/hip_runtime.h>
#include <hip/hip_bf16.h>

#define BB 32
#define SS 1600
#define DD 128
#define DFFN 2048
#define S2N 3200
#define RS 136  // LDS row stride in bf16 elems (128 + 8 pad)

typedef __attribute__((ext_vector_type(8))) short short8;
typedef __attribute__((ext_vector_type(4))) float floatx4;
typedef unsigned int u32;
typedef unsigned short u16;

__device__ __forceinline__ u32 encf(float f) {
  u32 u = __float_as_uint(f);
  return (u & 0x80000000u) ? ~u : (u | 0x80000000u);
}
__device__ __forceinline__ float decf(u32 e) {
  u32 u = (e & 0x80000000u) ? (e & 0x7fffffffu) : ~e;
  return __uint_as_float(u);
}
// fast RNE fp32->bf16 (finite data; matches library rounding)
__device__ __forceinline__ u16 f2b(float x) {
  u32 u = __float_as_uint(x);
  return (u16)((u + 0x7FFFu + ((u >> 16) & 1u)) >> 16);
}
__device__ __forceinline__ u32 packb2(float lo, float hi) {
  return (u32)f2b(lo) | ((u32)f2b(hi) << 16);
}
__device__ __forceinline__ float sigm(float x) { return 1.f / (1.f + __expf(-x)); }

// ---------------- K1: fused prep (r12 verbatim) ----------------
// blocks [0,800): q/k projection + l2norm (bf16 MFMA; w1 staged once->LDS sB)
// blocks [800,1476): gate tiles (PAIRED fragment layout) + m1u/m2u init
__global__ __launch_bounds__(256) void k_prep(const float* __restrict__ tgt,
                                              const float* __restrict__ memin,
                                              const float* __restrict__ w1,
                                              const float* __restrict__ b1,
                                              const float* __restrict__ se,
                                              u16* __restrict__ qb, u16* __restrict__ kb,
                                              u16* __restrict__ gT2,
                                              u32* __restrict__ m1u, u32* __restrict__ m2u) {
  __shared__ u16 sA[128 * RS];
  __shared__ u16 sB[128 * RS];
  __shared__ float sq[128];
  int tid = threadIdx.x;
  int lane = tid & 63, wv = tid >> 6;
  int wr = wv >> 1, wc = wv & 1;
  int l15 = lane & 15, lg = lane >> 4;

  if (blockIdx.x >= 800) {  // ---- gate-tile build + max-array init ----
    int bid = blockIdx.x - 800;       // 0..675
    int ii = bid * 256 + tid;
    if (ii < BB * SS) {  // 0 encodes "below every finite float"
      m1u[ii] = 0u;
      m2u[ii] = 0u;
    }
    int r2 = bid >> 2, mi = bid & 3;  // quarter-tile per block
    int sy = r2 / 13, tx = r2 - sy * 13;
    int s0 = min(sy * 128, SS - 128);
    int t0 = min(tx * 128, SS - 128);
    int srow = s0 + wr * 64 + mi * 16 + lg * 4;
    u16* tb = gT2 + (size_t)r2 * 16384 + wv * 4096 + lane * 8;
    for (int ni = 0; ni < 4; ++ni) {
      int tcol = t0 + wc * 64 + ni * 16 + l15;
      const float* sp = se + (size_t)srow * SS + tcol;
      ushort4 o;
      o.x = f2b(sigm(sp[0]));
      o.y = f2b(sigm(sp[SS]));
      o.z = f2b(sigm(sp[2 * SS]));
      o.w = f2b(sigm(sp[3 * SS]));
      *(ushort4*)(tb + (mi * 2 + (ni >> 1)) * 512 + (ni & 1) * 4) = o;
    }
    return;
  }

  // ---- projection ----
  long row0 = (long)blockIdx.x * 128;
  const float* src;
  u16* dst;
  if (row0 < (long)BB * SS) { src = tgt + row0 * DD; dst = qb + row0 * DD; }
  else { src = memin + (row0 - (long)BB * SS) * DD; dst = kb + (row0 - (long)BB * SS) * DD; }

  for (int p = 0; p < 16; ++p) {
    int r = p * 8 + (tid >> 5);
    int c4 = (tid & 31) * 4;
    float4 v = *(const float4*)(src + r * DD + c4);
    *(u32*)&sA[r * RS + c4] = packb2(v.x, v.y);
    *(u32*)&sA[r * RS + c4 + 2] = packb2(v.z, v.w);
    float4 w = *(const float4*)(w1 + r * DD + c4);
    *(u32*)&sB[r * RS + c4] = packb2(w.x, w.y);
    *(u32*)&sB[r * RS + c4 + 2] = packb2(w.z, w.w);
  }
  if (tid < 128) sq[tid] = 0.f;
  __syncthreads();

  floatx4 acc[4][4];
  for (int mi = 0; mi < 4; ++mi)
    for (int ni = 0; ni < 4; ++ni) acc[mi][ni] = (floatx4){0.f, 0.f, 0.f, 0.f};

  for (int kc = 0; kc < 4; ++kc) {
    int k0 = kc * 32 + lg * 8;
    short8 af[4], bfr[4];
    for (int mi = 0; mi < 4; ++mi) af[mi] = *(const short8*)&sA[(wr * 64 + mi * 16 + l15) * RS + k0];
    for (int ni = 0; ni < 4; ++ni) bfr[ni] = *(const short8*)&sB[(wc * 64 + ni * 16 + l15) * RS + k0];
    for (int mi = 0; mi < 4; ++mi)
      for (int ni = 0; ni < 4; ++ni)
        acc[mi][ni] = __builtin_amdgcn_mfma_f32_16x16x32_bf16(af[mi], bfr[ni], acc[mi][ni], 0, 0, 0);
  }

  float bvals[4];
  for (int ni = 0; ni < 4; ++ni) bvals[ni] = b1[wc * 64 + ni * 16 + l15];
  for (int mi = 0; mi < 4; ++mi)
    for (int r = 0; r < 4; ++r) {
      float s = 0.f;
      for (int ni = 0; ni < 4; ++ni) {
        float v = acc[mi][ni][r] + bvals[ni];
        acc[mi][ni][r] = v;
        s += v * v;
      }
      s += __shfl_xor(s, 1); s += __shfl_xor(s, 2);
      s += __shfl_xor(s, 4); s += __shfl_xor(s, 8);
      if (l15 == 0) atomicAdd(&sq[wr * 64 + mi * 16 + lg * 4 + r], s);
    }
  __syncthreads();

  for (int mi = 0; mi < 4; ++mi)
    for (int r = 0; r < 4; ++r) {
      int row = wr * 64 + mi * 16 + lg * 4 + r;
      float scale = 1.f / fmaxf(sqrtf(sq[row]), 1e-12f);
      for (int ni = 0; ni < 4; ++ni)
        sA[row * RS + wc * 64 + ni * 16 + l15] = f2b(acc[mi][ni][r] * scale);
    }
  __syncthreads();
  for (int p = 0; p < 8; ++p) {
    int r = p * 16 + (tid >> 4);
    int c8 = (tid & 15) * 8;
    *(uint4*)(dst + r * DD + c8) = *(const uint4*)&sA[r * RS + c8];
  }
}

// ---------------- K2: one 128x128 attn tile pair per block (r10/r12 verbatim, NO setprio) ----------------
__global__ __launch_bounds__(256, 4) void k_attn(const u16* __restrict__ qb,
                                                 const u16* __restrict__ kb,
                                                 const u16* __restrict__ gT2,
                                                 u32* __restrict__ m1u, u32* __restrict__ m2u) {
  __shared__ u16 sK[128 * RS];
  __shared__ float scmax[2][128];
  __shared__ float srmax[2][128];
  int tid = threadIdx.x;
  int n = blockIdx.x;  // 5408 = 8 XCDs * 169 tiles * 4 batches
  int m = n >> 3;      // 0..675
  int r2 = m >> 2;     // tile index, adjacent across the 4 batches
  int b = (n & 7) * 4 + (m & 3);
  int sy = r2 / 13, tx = r2 - sy * 13;
  int s0 = min(sy * 128, SS - 128);  // edge tiles clamp-overlap; max is idempotent
  int t0 = min(tx * 128, SS - 128);
  int lane = tid & 63, wv = tid >> 6;
  int wr = wv >> 1, wc = wv & 1;
  int l15 = lane & 15, lg = lane >> 4;
  const size_t base = (size_t)b * SS * DD;
  const u16* qp = qb + base + (size_t)(s0 + wr * 64 + l15) * DD + lg * 8;

  // K tile -> LDS
  {
    int rr0 = tid >> 4;
    int c8 = (tid & 15) * 8;
    const u16* kp = kb + base + (size_t)(t0 + rr0) * DD + c8;
    u16* sp = &sK[rr0 * RS + c8];
    for (int p = 0; p < 8; ++p)
      *(uint4*)(sp + p * 16 * RS) = *(const uint4*)(kp + (size_t)p * 16 * DD);
  }
  // first Q slice (kc=0)
  short8 qsA[4], qsB[4];
  for (int mi = 0; mi < 4; ++mi) qsA[mi] = *(const short8*)(qp + mi * 16 * DD);
  __syncthreads();

  floatx4 acc[4][4];
  for (int mi = 0; mi < 4; ++mi)
    for (int ni = 0; ni < 4; ++ni) acc[mi][ni] = (floatx4){0.f, 0.f, 0.f, 0.f};

#define QKSTEP(KC, CUR, NXT, PRE)                                                     \
  {                                                                                   \
    if (PRE)                                                                          \
      for (int mi = 0; mi < 4; ++mi)                                                  \
        NXT[mi] = *(const short8*)(qp + mi * 16 * DD + ((KC) + 1) * 32);              \
    int k0 = (KC)*32 + lg * 8;                                                        \
    short8 bfr[4];                                                                    \
    for (int ni = 0; ni < 4; ++ni)                                                    \
      bfr[ni] = *(const short8*)&sK[(wc * 64 + ni * 16 + l15) * RS + k0];             \
    for (int mi = 0; mi < 4; ++mi)                                                    \
      for (int ni = 0; ni < 4; ++ni)                                                  \
        acc[mi][ni] = __builtin_amdgcn_mfma_f32_16x16x32_bf16(CUR[mi], bfr[ni],       \
                                                              acc[mi][ni], 0, 0, 0);  \
  }
  QKSTEP(0, qsA, qsB, 1)
  QKSTEP(1, qsB, qsA, 1)
  QKSTEP(2, qsA, qsB, 1)
  QKSTEP(3, qsB, qsA, 0)
#undef QKSTEP

  // paired gate loads: 8 x uint4 (1KB/wave each), after MFMA so regs don't overlap qs/bfr
  uint4 g4[8];
  {
    const u16* gbase = gT2 + (size_t)r2 * 16384 + wv * 4096 + lane * 8;
    for (int p = 0; p < 8; ++p) g4[p] = *(const uint4*)(gbase + p * 512);
  }

  // gate multiply + row/col max
  float rmax[4][4];
  for (int mi = 0; mi < 4; ++mi)
    for (int r = 0; r < 4; ++r) rmax[mi][r] = -1e30f;
  float cmax[4];
  for (int ni = 0; ni < 4; ++ni) cmax[ni] = -1e30f;

  for (int mi = 0; mi < 4; ++mi)
    for (int ni = 0; ni < 4; ++ni) {
      uint4 pg = g4[mi * 2 + (ni >> 1)];
      u32 lo = (ni & 1) ? pg.z : pg.x;  // bf16 pair for r=0,1
      u32 hi = (ni & 1) ? pg.w : pg.y;  // bf16 pair for r=2,3
      float v0 = acc[mi][ni][0] * __uint_as_float(lo << 16);
      float v1 = acc[mi][ni][1] * __uint_as_float(lo & 0xffff0000u);
      float v2 = acc[mi][ni][2] * __uint_as_float(hi << 16);
      float v3 = acc[mi][ni][3] * __uint_as_float(hi & 0xffff0000u);
      rmax[mi][0] = fmaxf(rmax[mi][0], v0);
      rmax[mi][1] = fmaxf(rmax[mi][1], v1);
      rmax[mi][2] = fmaxf(rmax[mi][2], v2);
      rmax[mi][3] = fmaxf(rmax[mi][3], v3);
      cmax[ni] = fmaxf(cmax[ni], fmaxf(fmaxf(v0, v1), fmaxf(v2, v3)));
    }

  // column max: reduce over lg (rows) within wave, then across wr via LDS
  for (int ni = 0; ni < 4; ++ni) {
    cmax[ni] = fmaxf(cmax[ni], __shfl_xor(cmax[ni], 16));
    cmax[ni] = fmaxf(cmax[ni], __shfl_xor(cmax[ni], 32));
  }
  if (lane < 16)
    for (int ni = 0; ni < 4; ++ni) scmax[wr][wc * 64 + ni * 16 + lane] = cmax[ni];

  // row max: reduce over l15 (cols) within wave, then across wc via LDS
  for (int mi = 0; mi < 4; ++mi)
    for (int r = 0; r < 4; ++r) {
      float v = rmax[mi][r];
      v = fmaxf(v, __shfl_xor(v, 1));
      v = fmaxf(v, __shfl_xor(v, 2));
      v = fmaxf(v, __shfl_xor(v, 4));
      v = fmaxf(v, __shfl_xor(v, 8));
      if (l15 == 0) srmax[wc][wr * 64 + mi * 16 + lg * 4 + r] = v;
    }
  __syncthreads();

  if (tid < 128) {
    float v = fmaxf(scmax[0][tid], scmax[1][tid]);
    atomicMax(&m1u[b * SS + t0 + tid], encf(v));
  } else {
    int i2 = tid - 128;
    float v = fmaxf(srmax[0][i2], srmax[1][i2]);
    atomicMax(&m2u[b * SS + s0 + i2], encf(v));
  }
}

// ---------------- K3b: hacc[cs][b][f] = partial(BN1(x) @ w2^T), BN1 fused, 8-way split ----------------
__global__ __launch_bounds__(256) void k_gemm2(const u32* __restrict__ m1u,
                                               const u32* __restrict__ m2u,
                                               const float* __restrict__ g1,
                                               const float* __restrict__ be1,
                                               const float* __restrict__ w2,
                                               float* __restrict__ hacc) {
  int tid = threadIdx.x;
  int lane = tid & 63, wv = tid >> 6;
  int f0 = blockIdx.x * 32 + wv * 8;
  int cs = blockIdx.y;
  int cr0 = cs * 400;
  const u32* msrc = (cs < 4) ? m1u : m2u;
  int mcol0 = cr0 - ((cs < 4) ? 0 : SS);
  int c_sub = lane & 15, bq = lane >> 4;
  const float bnc = rsqrtf(1.f + 1e-5f);
  float acc[8][8];
  for (int a = 0; a < 8; ++a)
    for (int c = 0; c < 8; ++c) acc[a][c] = 0.f;
  const float4 z4 = {0.f, 0.f, 0.f, 0.f};
  for (int it = 0; it < 7; ++it) {
    int coff = it * 64 + c_sub * 4;
    bool ok = coff < 400;
    int cg = cr0 + coff;
    float4 w4[8], x4[8];
    float4 gv = ok ? *(const float4*)(g1 + cg) : z4;
    float4 bv = ok ? *(const float4*)(be1 + cg) : z4;
    gv.x *= bnc; gv.y *= bnc; gv.z *= bnc; gv.w *= bnc;
    for (int jf = 0; jf < 8; ++jf)
      w4[jf] = ok ? *(const float4*)(w2 + (size_t)(f0 + jf) * S2N + cg) : z4;
    for (int j = 0; j < 8; ++j) {
      if (ok) {
        uint4 e = *(const uint4*)(msrc + (size_t)(bq * 8 + j) * SS + mcol0 + coff);
        x4[j].x = decf(e.x) * gv.x + bv.x;
        x4[j].y = decf(e.y) * gv.y + bv.y;
        x4[j].z = decf(e.z) * gv.z + bv.z;
        x4[j].w = decf(e.w) * gv.w + bv.w;
      } else {
        x4[j] = z4;
      }
    }
    for (int jf = 0; jf < 8; ++jf)
      for (int j = 0; j < 8; ++j) {
        float a = acc[jf][j];
        a = fmaf(w4[jf].x, x4[j].x, a);
        a = fmaf(w4[jf].y, x4[j].y, a);
        a = fmaf(w4[jf].z, x4[j].z, a);
        a = fmaf(w4[jf].w, x4[j].w, a);
        acc[jf][j] = a;
      }
  }
  for (int jf = 0; jf < 8; ++jf)
    for (int j = 0; j < 8; ++j) {
      float v = acc[jf][j];
      v += __shfl_xor(v, 1); v += __shfl_xor(v, 2);
      v += __shfl_xor(v, 4); v += __shfl_xor(v, 8);
      acc[jf][j] = v;
    }
  if ((lane & 15) == 0) {
    for (int jf = 0; jf < 8; ++jf)
      for (int j = 0; j < 8; ++j) {
        int b = bq * 8 + j;
        hacc[((size_t)cs * BB + b) * DFFN + f0 + jf] = acc[jf][j];
      }
  }
}

// ---------------- K3c: BN2 + relu + dot w3 + BN3 ----------------
__global__ __launch_bounds__(256) void k_final(const float* __restrict__ hacc,
                                               const float* __restrict__ b2,
                                               const float* __restrict__ g2,
                                               const float* __restrict__ be2,
                                               const float* __restrict__ w3,
                                               const float* __restrict__ b3,
                                               const float* __restrict__ g3,
                                               const float* __restrict__ be3,
                                               float* __restrict__ out) {
  __shared__ float wsum[4];
  int b = blockIdx.x;
  int tid = threadIdx.x;
  float bnc = rsqrtf(1.f + 1e-5f);
  float part = 0.f;
  for (int f = tid; f < DFFN; f += 256) {
    float s = b2[f];
    for (int cs = 0; cs < 8; ++cs) s += hacc[((size_t)cs * BB + b) * DFFN + f];
    s = s * (g2[f] * bnc) + be2[f];
    s = fmaxf(s, 0.f);
    part += s * w3[f];
  }
  for (int m = 1; m < 64; m <<= 1) part += __shfl_xor(part, m);
  if ((tid & 63) == 0) wsum[tid >> 6] = part;
  __syncthreads();
  if (tid == 0) {
    float tot = wsum[0] + wsum[1] + wsum[2] + wsum[3] + b3[0];
    out[b] = tot * (g3[0] * bnc) + be3[0];
  }
}

extern "C" void kernel_launch(void* const* d_in, const int* in_sizes, int n_in,
                              void* d_out, int out_size, void* d_ws, size_t ws_size,
                              hipStream_t stream) {
  const float* tgt = (const float*)d_in[0];
  const float* memin = (const float*)d_in[1];
  const float* se = (const float*)d_in[2];
  const float* w1 = (const float*)d_in[3];
  const float* b1 = (const float*)d_in[4];
  const float* g1 = (const float*)d_in[5];
  const float* be1 = (const float*)d_in[6];
  const float* w2 = (const float*)d_in[7];
  const float* b2 = (const float*)d_in[8];
  const float* g2 = (const float*)d_in[9];
  const float* be2 = (const float*)d_in[10];
  const float* w3 = (const float*)d_in[11];
  const float* b3 = (const float*)d_in[12];
  const float* g3 = (const float*)d_in[13];
  const float* be3 = (const float*)d_in[14];
  float* out = (float*)d_out;

  char* ws = (char*)d_ws;
  const size_t OFF_GT = 0;                        // tiled bf16 gate: 169*16384*2 = 5,537,792
  const size_t OFF_QB = 5537792;                  // 13,107,200
  const size_t OFF_KB = OFF_QB + 13107200;
  const size_t OFF_M1 = OFF_KB + 13107200;        // 204,800
  const size_t OFF_M2 = OFF_M1 + 204800;
  const size_t OFF_HA = OFF_M2 + 204800;          // 8*32*2048*4 = 2,097,152
  const size_t NEEDED = OFF_HA + 2097152;
  if (ws_size < NEEDED) return;  // clean validation failure rather than OOB

  u16* gT2 = (u16*)(ws + OFF_GT);
  u16* qb = (u16*)(ws + OFF_QB);
  u16* kb = (u16*)(ws + OFF_KB);
  u32* m1u = (u32*)(ws + OFF_M1);
  u32* m2u = (u32*)(ws + OFF_M2);
  float* hacc = (float*)(ws + OFF_HA);

  k_prep<<<1476, 256, 0, stream>>>(tgt, memin, w1, b1, se, qb, kb, gT2, m1u, m2u);
  k_attn<<<5408, 256, 0, stream>>>(qb, kb, gT2, m1u, m2u);
  k_gemm2<<<dim3(64, 8), 256, 0, stream>>>(m1u, m2u, g1, be1, w2, hacc);
  k_final<<<32, 256, 0, stream>>>(hacc, b2, g2, be2, w3, b3, g3, be3, out);
}